// Round 2
// baseline (2864.800 us; speedup 1.0000x reference)
//
#include <hip/hip_runtime.h>

typedef unsigned short u16;
typedef __attribute__((ext_vector_type(8))) short bf8;
typedef __attribute__((ext_vector_type(4))) float fx4;

#define N_ENT   100000
#define N_EDGE  500000
#define N_TEST  131072
#define EDIM    200

// ---------- helpers ----------
__device__ __forceinline__ u16 f2bf(float f) {
  union { float f; unsigned u; } c; c.f = f;
  return (u16)((c.u + 0x7FFFu + ((c.u >> 16) & 1u)) >> 16);  // RNE
}
__device__ __forceinline__ float bf2f(u16 h) {
  union { unsigned u; float f; } c; c.u = ((unsigned)h) << 16;
  return c.f;
}
__device__ __forceinline__ float wave_sum(float s) {
  #pragma unroll
  for (int off = 32; off > 0; off >>= 1) s += __shfl_xor(s, off, 64);
  return s;
}

// ---------- generic bf16 MFMA GEMM: out = act(A @ B^T + bias) ----------
// A: [M, lda] bf16 (row-major), B: [Npad, ldb] bf16 (row n = column n of the math-B)
// 128x128 tile, 256 thr = 4 waves in 2x2, each wave 4x4 16x16x32 MFMAs.
#define BM 128
#define BN 128
#define BK 32
#define LDS_T 40   // 32 + 8 pad (keeps 16B alignment, breaks pow2 bank stride)

__global__ __launch_bounds__(256) void gemm_bf16(
    const u16* __restrict__ A, long lda,
    const u16* __restrict__ B, long ldb,
    u16* __restrict__ out, long ldOut,
    int K, int kValid,
    const int* __restrict__ rowIdx, int mClamp,
    int mValid, int nValid, int nStore, int colOff,
    const float* __restrict__ bias, int act, float slope)
{
  __shared__ __align__(16) u16 As[BM][LDS_T];
  __shared__ __align__(16) u16 Bs[BN][LDS_T];
  const int tid  = threadIdx.x;
  const int wave = tid >> 6, lane = tid & 63;
  const int wr = (wave >> 1) * 64, wc = (wave & 1) * 64;
  const int fr = lane & 15, fq = lane >> 4;
  const long bm = (long)blockIdx.x * BM, bn = (long)blockIdx.y * BN;
  const int lr = tid >> 2;          // 0..63 staging row
  const int lc = (tid & 3) * 8;     // 0,8,16,24 staging col (8 bf16 = 16B)

  fx4 zero4 = {0.f, 0.f, 0.f, 0.f};
  fx4 acc[4][4];
  #pragma unroll
  for (int i = 0; i < 4; ++i)
    #pragma unroll
    for (int j = 0; j < 4; ++j) acc[i][j] = zero4;

  long aro[2], bro[2];
  #pragma unroll
  for (int h = 0; h < 2; ++h) {
    long gm = bm + lr + h * 64;
    if (rowIdx) gm = rowIdx[gm];               // gather rows (te = all_ent[toTest])
    else if (gm >= mClamp) gm = mClamp - 1;    // clamp: values unused (store-guarded)
    aro[h] = gm * lda;
    bro[h] = (bn + lr + h * 64) * ldb;
  }

  bf8 zv = {0, 0, 0, 0, 0, 0, 0, 0};
  for (int k0 = 0; k0 < K; k0 += BK) {
    bf8 av[2], bv[2];
    const bool kok = (k0 + lc) < kValid;       // chunk boundaries are multiples of 8
    #pragma unroll
    for (int h = 0; h < 2; ++h) {
      av[h] = kok ? *(const bf8*)(A + aro[h] + k0 + lc) : zv;
      bv[h] = *(const bf8*)(B + bro[h] + k0 + lc);
    }
    __syncthreads();
    #pragma unroll
    for (int h = 0; h < 2; ++h) {
      *(bf8*)&As[lr + h * 64][lc] = av[h];
      *(bf8*)&Bs[lr + h * 64][lc] = bv[h];
    }
    __syncthreads();
    bf8 aF[4], bF[4];
    #pragma unroll
    for (int mt = 0; mt < 4; ++mt) aF[mt] = *(const bf8*)&As[wr + mt * 16 + fr][fq * 8];
    #pragma unroll
    for (int nt = 0; nt < 4; ++nt) bF[nt] = *(const bf8*)&Bs[wc + nt * 16 + fr][fq * 8];
    #pragma unroll
    for (int mt = 0; mt < 4; ++mt)
      #pragma unroll
      for (int nt = 0; nt < 4; ++nt)
        acc[mt][nt] = __builtin_amdgcn_mfma_f32_16x16x32_bf16(aF[mt], bF[nt], acc[mt][nt], 0, 0, 0);
  }

  // epilogue: C/D layout col=lane&15, row=(lane>>4)*4+reg  [m89-verified]
  #pragma unroll
  for (int mt = 0; mt < 4; ++mt) {
    #pragma unroll
    for (int r = 0; r < 4; ++r) {
      const long gm = bm + wr + mt * 16 + fq * 4 + r;
      if (gm >= mValid) continue;
      #pragma unroll
      for (int nt = 0; nt < 4; ++nt) {
        const long gn = bn + wc + nt * 16 + fr;
        if (gn >= nStore) continue;
        float v = 0.f;
        if (gn < nValid) {
          v = acc[mt][nt][r];
          if (bias) v += bias[gn];
          if (act == 1) v = tanhf(v);
          else if (act == 2) v = (v >= 0.f) ? v : v * slope;
        }
        out[gm * ldOut + colOff + gn] = f2bf(v);
      }
    }
  }
}

// ---------- stage A: edge scatter (pre-W aggregation; segsum is linear vs @W) ----------
__global__ void scatter_kernel(const int* __restrict__ ei, const int* __restrict__ et,
                               const float* __restrict__ ent_emb, const float* __restrict__ rel_emb,
                               float* __restrict__ agg, float* __restrict__ deg)
{
  const int wave = threadIdx.x >> 6, lane = threadIdx.x & 63;
  const int e = blockIdx.x * 4 + wave;
  if (e >= N_EDGE) return;
  const int src = ei[e], dst = ei[N_EDGE + e], t = et[e];
  if (lane == 0) unsafeAtomicAdd(&deg[dst], 1.0f);
  const float* se = ent_emb + (size_t)src * EDIM;
  const float* re = rel_emb + (size_t)t * EDIM;
  float* ar = agg + (size_t)dst * EDIM;
  for (int d = lane; d < EDIM; d += 64)
    unsafeAtomicAdd(&ar[d], se[d] - re[d]);
}

// ---------- builders ----------
// A1 [100000][416]: cols 0..199 = agg*norm, 200..399 = ent_emb  (400..415 never read: kValid=400)
__global__ void build_A1(const float* __restrict__ agg, const float* __restrict__ deg,
                         const float* __restrict__ ent_emb, u16* __restrict__ A1)
{
  long idx = (long)blockIdx.x * 256 + threadIdx.x;
  if (idx >= (long)N_ENT * 400) return;
  int r = (int)(idx / 400), c = (int)(idx % 400);
  float v;
  if (c < 200) v = agg[(size_t)r * EDIM + c] * rsqrtf(fmaxf(deg[r], 1.0f));
  else         v = ent_emb[(size_t)r * EDIM + (c - 200)];
  A1[(size_t)r * 416 + c] = f2bf(v);
}

// B1T [256][416]: row n = [W[:,n] ; W_loop[:,n] ; 0]
__global__ void build_B1T(const float* __restrict__ W, const float* __restrict__ W_loop,
                          u16* __restrict__ B1T)
{
  int idx = blockIdx.x * 256 + threadIdx.x;
  if (idx >= 256 * 416) return;
  int n = idx / 416, k = idx % 416;
  float v = 0.f;
  if (n < 200) {
    if (k < 200) v = W[k * 200 + n];
    else if (k < 400) v = W_loop[(k - 200) * 200 + n];
  }
  B1T[idx] = f2bf(v);
}

// B2T [128][224]: trans_w^T, zero-padded
__global__ void build_B2T(const float* __restrict__ trans_w, u16* __restrict__ B2T)
{
  int idx = blockIdx.x * 256 + threadIdx.x;
  if (idx >= 128 * 224) return;
  int n = idx / 224, k = idx % 224;
  float v = (n < 100 && k < 200) ? trans_w[k * 100 + n] : 0.f;
  B2T[idx] = f2bf(v);
}

// all_rel = rel_emb @ W_rel  (tiny, f32)
__global__ void all_rel_kernel(const float* __restrict__ rel_emb, const float* __restrict__ W_rel,
                               float* __restrict__ all_rel)
{
  int r = blockIdx.x, c = threadIdx.x;
  if (c >= 200) return;
  const float* re = rel_emb + r * 200;
  float a = 0.f;
  for (int k = 0; k < 200; ++k) a += re[k] * W_rel[k * 200 + c];
  all_rel[r * 200 + c] = a;
}

// B4T [512][256]: row r = [head_rel[r] (100) | 0(28) | -tail_rel[r] (100) | 0(28)]
__global__ void build_B4T(const float* __restrict__ all_rel, u16* __restrict__ B4T)
{
  int idx = blockIdx.x * 256 + threadIdx.x;
  if (idx >= 512 * 256) return;
  int n = idx / 256, k = idx % 256;
  float v = 0.f;
  if (n < 474) {
    if (k < 100) v = all_rel[n * 200 + k];
    else if (k >= 128 && k < 228) v = -all_rel[n * 200 + 100 + (k - 128)];
  }
  B4T[idx] = f2bf(v);
}

// w1T [2048][896], w2T [512][2048]
__global__ void build_w1T(const float* __restrict__ w1, u16* __restrict__ w1T)
{
  long idx = (long)blockIdx.x * 256 + threadIdx.x;
  if (idx >= (long)2048 * 896) return;
  int n = (int)(idx / 896), k = (int)(idx % 896);
  w1T[idx] = f2bf(k < 875 ? w1[(size_t)k * 2048 + n] : 0.f);
}
__global__ void build_w2T(const float* __restrict__ w2, u16* __restrict__ w2T)
{
  long idx = (long)blockIdx.x * 256 + threadIdx.x;
  if (idx >= (long)512 * 2048) return;
  int n = (int)(idx / 2048), k = (int)(idx % 2048);
  w2T[idx] = f2bf(w2[(size_t)k * 512 + n]);
}

// ---------- atta: per-pair attention scalar ----------
__global__ void atta_kernel(const u16* __restrict__ ee,
                            const float* __restrict__ q_w, const float* __restrict__ q_b,
                            const float* __restrict__ k_w, const float* __restrict__ k_b,
                            float* __restrict__ atta)
{
  __shared__ u16 wq[100 * 256];   // [k][j]: j<128 = q_w, j>=128 = k_w
  for (int idx = threadIdx.x; idx < 100 * 256; idx += 256) {
    int k = idx >> 8, j = idx & 255;
    float v = (j < 128) ? q_w[k * 128 + j] : k_w[k * 128 + (j - 128)];
    wq[idx] = f2bf(v);
  }
  __syncthreads();
  const int wave = threadIdx.x >> 6, lane = threadIdx.x & 63;
  for (int rr = 0; rr < 8; ++rr) {
    const int i = blockIdx.x * 32 + wave * 8 + rr;
    const u16* he = ee + (size_t)(2 * i) * 128;
    const u16* te = he + 128;
    float q0 = 0.f, q1 = 0.f, p0 = 0.f, p1 = 0.f;
    for (int k = 0; k < 100; ++k) {
      float h = bf2f(he[k]), t = bf2f(te[k]);
      const u16* w = wq + k * 256;
      q0 += h * bf2f(w[lane]);
      q1 += h * bf2f(w[64 + lane]);
      p0 += t * bf2f(w[128 + lane]);
      p1 += t * bf2f(w[192 + lane]);
    }
    float s = (q0 + q_b[lane]) * (p0 + k_b[lane]) + (q1 + q_b[64 + lane]) * (p1 + k_b[64 + lane]);
    s = wave_sum(s);
    if (lane == 0) atta[i] = s * 0.07071067811865475f;   // 1/sqrt(200)
  }
}

// ---------- cat builder (per chunk): cols 0..400 and 875..895 pad (relSim fills 401..874) ----------
__global__ void cat_build(const u16* __restrict__ all_ent, const int* __restrict__ toTest,
                          const float* __restrict__ atta, u16* __restrict__ cat)
{
  const int i = blockIdx.x;
  const int t0 = toTest[2 * i], t1 = toTest[2 * i + 1];
  u16* row = cat + (size_t)i * 896;
  for (int j = threadIdx.x; j < 422; j += 256) {
    u16 v = 0;
    int col;
    if (j < 200)      { v = all_ent[(size_t)t0 * 200 + j]; col = j; }
    else if (j < 400) { v = all_ent[(size_t)t1 * 200 + (j - 200)]; col = j; }
    else if (j == 400){ v = f2bf(atta[i]); col = 400; }
    else              { col = 875 + (j - 401); }           // zero pad
    row[col] = v;
  }
}

// ---------- final head: sigmoid(h2 @ w3 + b3) ----------
__global__ void out_head(const u16* __restrict__ h2, const float* __restrict__ w3,
                         const float* __restrict__ b3, float* __restrict__ out)
{
  const int wave = threadIdx.x >> 6, lane = threadIdx.x & 63;
  const int i = blockIdx.x * 4 + wave;
  const u16* hr = h2 + (size_t)i * 512;
  bf8 hv = *(const bf8*)(hr + lane * 8);
  float s = 0.f;
  #pragma unroll
  for (int j = 0; j < 8; ++j) s += bf2f((u16)hv[j]) * w3[lane * 8 + j];
  s = wave_sum(s);
  if (lane == 0) out[i] = 1.f / (1.f + __expf(-(s + b3[0])));
}

// ---------- host ----------
extern "C" void kernel_launch(void* const* d_in, const int* in_sizes, int n_in,
                              void* d_out, int out_size, void* d_ws, size_t ws_size,
                              hipStream_t stream)
{
  (void)in_sizes; (void)n_in; (void)out_size;
  const int*   edge_index = (const int*)d_in[0];
  const int*   edge_type  = (const int*)d_in[1];
  const int*   toTest     = (const int*)d_in[2];
  const float* ent_emb    = (const float*)d_in[3];
  const float* rel_emb    = (const float*)d_in[4];
  const float* W          = (const float*)d_in[5];
  const float* W_loop     = (const float*)d_in[6];
  const float* W_rel      = (const float*)d_in[7];
  const float* trans_w    = (const float*)d_in[8];
  const float* trans_b    = (const float*)d_in[9];
  const float* q_w        = (const float*)d_in[10];
  const float* q_b        = (const float*)d_in[11];
  const float* k_w        = (const float*)d_in[12];
  const float* k_b        = (const float*)d_in[13];
  const float* w1         = (const float*)d_in[14];
  const float* b1         = (const float*)d_in[15];
  const float* w2         = (const float*)d_in[16];
  const float* b2         = (const float*)d_in[17];
  const float* w3         = (const float*)d_in[18];
  const float* b3         = (const float*)d_in[19];
  float* out = (float*)d_out;

  // ---- adaptive workspace layout (lifetime overlays) ----
  // P (persist small):   [0 .. 7,203,328)
  // X (80,400,384):      agg+deg (phase 1-2)  ->  all_ent (phase 3+)
  // Y (83,200,000):      A1      (phase 1-3)  ->  ee + nothing (phase 4+)
  // Z (CH*6912):         catChunk | h1 | h2   (MLP loop, chunk of CH rows)
  unsigned char* ws = (unsigned char*)d_ws;
  float* atta    = (float*)(ws + 0);            //   524,288
  float* allrel  = (float*)(ws + 524288);       //   379,392 (474*200*4 padded)
  u16*   B1T     = (u16*)  (ws + 903680);       //   212,992
  u16*   B2T     = (u16*)  (ws + 1116672);      //    57,344
  u16*   B4T     = (u16*)  (ws + 1174016);      //   262,144
  u16*   w1T     = (u16*)  (ws + 1436160);      // 3,670,016
  u16*   w2T     = (u16*)  (ws + 5106176);      // 2,097,152
  const size_t X_base = 7203328;
  float* agg     = (float*)(ws + X_base);       // 80,000,000 (dead after build_A1)
  float* deg     = (float*)(ws + X_base + 80000000); // 400,000
  u16*   all_ent = (u16*)  (ws + X_base);       // 40,000,000 (overlays dead agg)
  const size_t Y_base = 87603712;               // X_base + 80,400,384
  u16*   A1      = (u16*)  (ws + Y_base);       // 83,200,000 (dead after GEMM1)
  u16*   ee      = (u16*)  (ws + Y_base);       // 67,108,864 (overlays dead A1)
  const size_t Z_base = 170803712;              // Y_base + 83,200,000

  // chunk rows for the relSim/cat/MLP pipeline: largest that fits ws_size
  int CH;
  if      (Z_base + (size_t)32768 * 6912 <= ws_size) CH = 32768;
  else if (Z_base + (size_t)16384 * 6912 <= ws_size) CH = 16384;
  else if (Z_base + (size_t)8192  * 6912 <= ws_size) CH = 8192;
  else if (Z_base + (size_t)4096  * 6912 <= ws_size) CH = 4096;
  else if (Z_base + (size_t)2048  * 6912 <= ws_size) CH = 2048;
  else return;  // workspace too small for this plan (harness will report absmax fail)

  u16* catChunk = (u16*)(ws + Z_base);                          // CH*896*2
  u16* h1       = (u16*)(ws + Z_base + (size_t)CH * 1792);      // CH*2048*2
  u16* h2       = (u16*)(ws + Z_base + (size_t)CH * 5888);      // CH*512*2
  const int NC = N_TEST / CH;

  hipMemsetAsync(agg, 0, (size_t)N_ENT * EDIM * 4, stream);
  hipMemsetAsync(deg, 0, (size_t)N_ENT * 4, stream);

  scatter_kernel<<<N_EDGE / 4, 256, 0, stream>>>(edge_index, edge_type, ent_emb, rel_emb, agg, deg);
  build_A1<<<(N_ENT * 400 + 255) / 256, 256, 0, stream>>>(agg, deg, ent_emb, A1);
  build_B1T<<<(256 * 416) / 256, 256, 0, stream>>>(W, W_loop, B1T);

  // all_ent = tanh([agg*norm | ent] @ [W ; W_loop]) -> bf16 [100000][200]   (writes over dead agg)
  gemm_bf16<<<dim3(782, 2), 256, 0, stream>>>(A1, 416, B1T, 416, all_ent, 200,
      416, 400, nullptr, N_ENT, N_ENT, 200, 200, 0, nullptr, 1, 0.f);

  all_rel_kernel<<<474, 256, 0, stream>>>(rel_emb, W_rel, allrel);
  build_B2T<<<(128 * 224) / 256, 256, 0, stream>>>(trans_w, B2T);
  build_B4T<<<(512 * 256) / 256, 256, 0, stream>>>(allrel, B4T);
  build_w1T<<<(2048 * 896) / 256, 256, 0, stream>>>(w1, w1T);
  build_w2T<<<(512 * 2048) / 256, 256, 0, stream>>>(w2, w2T);

  // ee[j] = all_ent[toTest_flat[j]] @ trans_w + trans_b  -> bf16 [262144][128]  (over dead A1)
  gemm_bf16<<<dim3(2048, 1), 256, 0, stream>>>(all_ent, 200, B2T, 224, ee, 128,
      224, 200, toTest, 2 * N_TEST, 2 * N_TEST, 100, 128, 0, trans_b, 0, 0.f);

  atta_kernel<<<N_TEST / 32, 256, 0, stream>>>(ee, q_w, q_b, k_w, k_b, atta);

  // per-chunk: relSim GEMM -> catChunk cols 401..874; cat_build fills the rest; then MLP + head
  for (int c = 0; c < NC; ++c) {
    const u16* eeC = ee + (size_t)c * CH * 256;   // ee viewed as [131072][256]
    gemm_bf16<<<dim3(CH / 128, 4), 256, 0, stream>>>(eeC, 256, B4T, 256, catChunk, 896,
        256, 256, nullptr, CH, CH, 474, 474, 401, nullptr, 0, 0.f);

    cat_build<<<CH, 256, 0, stream>>>(all_ent, toTest + (size_t)c * CH * 2,
                                      atta + (size_t)c * CH, catChunk);

    gemm_bf16<<<dim3(CH / 128, 16), 256, 0, stream>>>(catChunk, 896, w1T, 896, h1, 2048,
        896, 896, nullptr, CH, CH, 2048, 2048, 0, b1, 2, 0.0001f);
    gemm_bf16<<<dim3(CH / 128, 4), 256, 0, stream>>>(h1, 2048, w2T, 2048, h2, 512,
        2048, 2048, nullptr, CH, CH, 512, 512, 0, b2, 2, 0.001f);
    out_head<<<CH / 4, 256, 0, stream>>>(h2, w3, b3, out + (size_t)c * CH);
  }
}